// Round 7
// baseline (467.621 us; speedup 1.0000x reference)
//
#include <hip/hip_runtime.h>

// VQ-VAE vector quantizer, MI355X (gfx950)
// B=16, C=256, H=W=32 -> N=16384 pixels; K=8192 codes.
// R10: R9 (A-in-regs, unconstrained) landed 264 unified -> 1 wave/SIMD,
// 372us, 70% vmcnt stall. R7 (A-from-LDS, 2 waves) = 345us. Cross-round
// triangulation: the wall is B-stream latency, hidden only by occupancy;
// LDS removal is worthless at 1 wave/SIMD but compounds at 2. Fix: keep
// A-in-regs AND hit 2 waves/SIMD by making the waves_per_eu(2) 128/128
// arch/acc split land exactly: aA (128 regs) -> acc half (backend spills
// VGPR overflow to free AGPRs as cheap v_accvgpr movs; gfx950 MFMA reads
// A from AGPR natively), and trim non-aA arch below 128 via kt=1
// (acc 32->16, B in-flight halved): arch ~95-110 + acc 128 = ~240 <= 256.
// Geometry: 4 waves = 2 wh x 2 wk, 32px x 16 codes/iter, 32 iters.
// Numerics bit-identical to R7/R9: kt was an outer repeat, not part of
// any accumulation chain; same 8-step cs MFMA chain per code, same
// epilogue rounding, index-ordered ties, monotone-k per wave.
// Canaries: k_score WRITE_SIZE ~1MB (scratch spill => AGPR placement
// failed -> revert to R7+trim), FETCH ~70-85MB (L2 thrash).

typedef _Float16 f16;
typedef __attribute__((ext_vector_type(8))) _Float16 f16x8;
typedef __attribute__((ext_vector_type(4))) float f32x4;

#define NPIX   16384      // B*H*W
#define CDIM   256
#define KCODE  8192

// ---------------- K0: fused prep ----------------
// bid <  512 : codebook -> packed MFMA B-fragments (hi/lo limbs, x8192)
// bid <  576 : z -> zhi/zlo fp16 limbs + z_sq (bit-exact pairwise)
// bid <  608 : e_sq (bit-exact numpy pairwise, thread per row)
__global__ void k_prep(const float* __restrict__ z, const float* __restrict__ cb,
                       f16* __restrict__ zhi, f16* __restrict__ zlo,
                       float* __restrict__ zsq,
                       f16* __restrict__ bfh, f16* __restrict__ bfl,
                       float* __restrict__ esq) {
  int bid = blockIdx.x;
  int t   = threadIdx.x;
  if (bid < 512) {
    // ---- cbsplit: bf[((kb*8+cs)*64+lane)*8+j] =
    //      limb(cb[kb*16+(lane&15)][cs*32+((lane>>4)&3)*8+j]) ----
    int kb = bid;
#pragma unroll
    for (int half = 0; half < 2; ++half) {
      int o    = half * 256 + t;         // o = cs*64 + lane, 0..511
      int lane = o & 63;
      int cs   = o >> 6;
      int code = kb * 16 + (lane & 15);
      int c0   = cs * 32 + ((lane >> 4) & 3) * 8;
      const float* src = cb + (size_t)code * CDIM + c0;
      float4 v0 = *(const float4*)(src);
      float4 v1 = *(const float4*)(src + 4);
      float e[8] = {v0.x, v0.y, v0.z, v0.w, v1.x, v1.y, v1.z, v1.w};
      f16x8 h8, l8;
#pragma unroll
      for (int j = 0; j < 8; ++j) {
        float ej = e[j] * 8192.0f;
        f16 h = (f16)ej;
        h8[j] = h;
        l8[j] = (f16)((ej - (float)h) * 4096.0f);
      }
      size_t off = ((size_t)kb * 512 + o) * 8;
      *(f16x8*)(bfh + off) = h8;
      *(f16x8*)(bfl + off) = l8;
    }
  } else if (bid < 576) {
    // ---- zprep: limbs + zsq (numpy pairwise fp32 order, contract off) ----
#pragma clang fp contract(off)
    int n = (bid - 512) * 256 + t;
    int b = n >> 10, p = n & 1023;
    const float* src = z + (size_t)b * CDIM * 1024 + p;
    f16* dh = zhi + (size_t)n * CDIM;
    f16* dl = zlo + (size_t)n * CDIM;
    float half_[2];
    for (int m = 0; m < 2; ++m) {
      float r[8];
#pragma unroll
      for (int j = 0; j < 8; ++j) r[j] = 0.0f;
      for (int i = 0; i < 16; ++i) {
        f16x8 h8, l8;
#pragma unroll
        for (int j = 0; j < 8; ++j) {
          float v = src[(size_t)(m * 128 + i * 8 + j) * 1024];  // coalesced
          r[j] = r[j] + v * v;                                  // mul then add
          f16 h = (f16)v;
          h8[j] = h;
          l8[j] = (f16)((v - (float)h) * 4096.0f);              // scaled low limb
        }
        *(f16x8*)(dh + m * 128 + i * 8) = h8;
        *(f16x8*)(dl + m * 128 + i * 8) = l8;
      }
      half_[m] = ((r[0] + r[1]) + (r[2] + r[3])) + ((r[4] + r[5]) + (r[6] + r[7]));
    }
    zsq[n] = half_[0] + half_[1];
  } else {
    // ---- esq: bit-exact numpy pairwise ----
#pragma clang fp contract(off)
    int row = (bid - 576) * 256 + t;
    const float* src = cb + (size_t)row * CDIM;
    float half_[2];
    for (int m = 0; m < 2; ++m) {
      float r[8];
#pragma unroll
      for (int j = 0; j < 8; ++j) r[j] = 0.0f;
      for (int i = 0; i < 16; ++i) {
        float4 v0 = *(const float4*)(src + m * 128 + i * 8);
        float4 v1 = *(const float4*)(src + m * 128 + i * 8 + 4);
        r[0] = r[0] + v0.x * v0.x;  r[1] = r[1] + v0.y * v0.y;
        r[2] = r[2] + v0.z * v0.z;  r[3] = r[3] + v0.w * v0.w;
        r[4] = r[4] + v1.x * v1.x;  r[5] = r[5] + v1.y * v1.y;
        r[6] = r[6] + v1.z * v1.z;  r[7] = r[7] + v1.w * v1.w;
      }
      half_[m] = ((r[0] + r[1]) + (r[2] + r[3])) + ((r[4] + r[5]) + (r[6] + r[7]));
    }
    esq[row] = half_[0] + half_[1];
  }
}

// ---------------- K2: fused score GEMM + argmin ----------------
// 2048 blocks x 256 threads (4 waves = 2 wh x 2 wk). Job = (kslice, ptile)
// claimed at runtime: kslice = this block's actual XCD id (1 MB hi+lo
// packed codebook slice stays L2-resident per XCD), ptile = per-slice
// ticket. Pigeonhole: a block seeing all 8 counters >= 256 implies 2048
// claims by others -- impossible with 2048 blocks each claiming <= 1.
// A-tile 64px x 256c hi+lo staged through 64KB LDS (16B xor swizzle) in
// the PROLOGUE ONLY: each wave reads its 32 A-fragments (128 regs ->
// acc half) once; the 32-iter main loop is pure {2 B-loads + 3 MFMA}
// per cs -- zero ds_read, minimal address VALU.
__launch_bounds__(256)
__attribute__((amdgpu_waves_per_eu(2)))
__global__ void k_score(const f16* __restrict__ bfh, const f16* __restrict__ bfl,
                        const f16* __restrict__ zhi, const f16* __restrict__ zlo,
                        const float* __restrict__ esq, const float* __restrict__ zsq,
                        int* __restrict__ cnt,
                        unsigned long long* __restrict__ best) {
  extern __shared__ char smem[];
  f16* sAh = (f16*)smem;               // 32 KB
  f16* sAl = (f16*)(smem + 32768);     // 32 KB
  int t = threadIdx.x;
  int wave = t >> 6, lane = t & 63;
  int quad = lane >> 4, l15 = lane & 15;
  int wh = wave & 1;                   // pixel half: rows [wh*32, wh*32+32)
  int wk = wave >> 1;                  // code strip 0..1

  // ---- claim (kslice, ptile) aligned to the real XCD ----
  __shared__ int s_job[2];
  if (t == 0) {
    unsigned xcc;
    asm volatile("s_getreg_b32 %0, hwreg(HW_REG_XCC_ID)" : "=s"(xcc));
    int x = (int)(xcc & 7u);
    int pt = -1, ks = 0;
    for (int trial = 0; trial < 16 && pt < 0; ++trial) {
      int j = (x + trial) & 7;
      int tk = atomicAdd(&cnt[j], 1);
      if (tk < 256) { pt = tk; ks = j; }
    }
    if (pt < 0) pt = 0;                // unreachable (see proof above)
    s_job[0] = pt; s_job[1] = ks;
  }
  __syncthreads();
  int ptile  = s_job[0];
  int kslice = s_job[1];
  int p0 = ptile * 64;

  // ---- stage A-tile (hi & lo), xor-swizzled at 16B granularity ----
  {
    int r = t >> 2, seg = t & 3;
    const uint4* gh = (const uint4*)zhi + ((size_t)(p0 + r)) * 32;
    const uint4* gl = (const uint4*)zlo + ((size_t)(p0 + r)) * 32;
    uint4* sh = (uint4*)sAh + r * 32;
    uint4* sl = (uint4*)sAl + r * 32;
#pragma unroll
    for (int j = 0; j < 8; ++j) {
      int blk = seg * 8 + j;
      int sb = blk ^ (r & 7);
      sh[sb] = gh[blk];
      sl[sb] = gl[blk];
    }
  }

  // Z for my 8 pixel rows (C/D layout: row = quad*4 + reg)
  float Zr[8];
#pragma unroll
  for (int rt = 0; rt < 2; ++rt)
#pragma unroll
    for (int rr = 0; rr < 4; ++rr)
      Zr[rt * 4 + rr] = zsq[p0 + wh * 32 + rt * 16 + quad * 4 + rr];

  __syncthreads();

  // ---- prologue: hoist this wave's entire A-half into registers ----
  // Same swizzled addresses as R7's in-loop reads; values identical.
  // 32 f16x8 = 128 regs, expected to land in the acc half under the
  // waves_per_eu(2) 128/128 split (MFMA reads A from AGPR natively).
  f16x8 aA[2][8][2];                   // [rt][cs][limb]
#pragma unroll
  for (int cs = 0; cs < 8; ++cs)
#pragma unroll
    for (int rt = 0; rt < 2; ++rt) {
      int px = wh * 32 + rt * 16 + l15;
      int sb = (cs * 4 + quad) ^ (px & 7);
      int eo = px * 256 + sb * 8;          // f16 units
      aA[rt][cs][0] = *(const f16x8*)(sAh + eo);
      aA[rt][cs][1] = *(const f16x8*)(sAl + eo);
    }

  float bs[8];
  int   bi[8];
#pragma unroll
  for (int j = 0; j < 8; ++j) { bs[j] = 3.0e38f; bi[j] = 0; }

  const f32x4 vzero = {0.0f, 0.0f, 0.0f, 0.0f};

#pragma unroll 1
  for (int iter = 0; iter < 32; ++iter) {
    int kbase = kslice * 1024 + iter * 32 + wk * 16;
    int kbq   = (kbase >> 4);          // 16-code block index
    f32x4 hh[2], mx[2];
#pragma unroll
    for (int rt = 0; rt < 2; ++rt) { hh[rt] = vzero; mx[rt] = vzero; }

#pragma unroll
    for (int cs = 0; cs < 8; ++cs) {
      f16x8 bh, bl;
      {
        size_t off = (((size_t)kbq * 8 + cs) * 64 + lane) * 8;
        bh = *(const f16x8*)(bfh + off);     // contiguous 1KB per wave
        bl = *(const f16x8*)(bfl + off);
      }
#pragma unroll
      for (int rt = 0; rt < 2; ++rt) {
        hh[rt] = __builtin_amdgcn_mfma_f32_16x16x32_f16(aA[rt][cs][0], bh, hh[rt], 0, 0, 0);
        mx[rt] = __builtin_amdgcn_mfma_f32_16x16x32_f16(aA[rt][cs][0], bl, mx[rt], 0, 0, 0);
        mx[rt] = __builtin_amdgcn_mfma_f32_16x16x32_f16(aA[rt][cs][1], bh, mx[rt], 0, 0, 0);
      }
    }

    // epilogue: replicate ref's fp32 rounding: d = fl(fl(Z - 2c) + es)
    // 2c = hh/4096 (exact scale) + mx/2^24 (one fmaf rounding)
    {
      int k = kbase + l15;
      float es = esq[k];
#pragma unroll
      for (int rt = 0; rt < 2; ++rt)
#pragma unroll
        for (int rr = 0; rr < 4; ++rr) {
          float v = hh[rt][rr] * 2.44140625e-4f;                           // /4096, exact
          float w = fmaf(mx[rt][rr], 5.9604644775390625e-8f, v);           // ~2*cross
          float d = (Zr[rt * 4 + rr] - w) + es;                            // two fp32 roundings
          int j = rt * 4 + rr;
          if (d < bs[j]) { bs[j] = d; bi[j] = k; }                         // first-index on ties
        }
    }
  }

  // ---- reduce: 16 lanes of each quad -> LDS -> across waves ----
  __syncthreads();                          // A-tile dead; reuse LDS
  unsigned long long* red = (unsigned long long*)smem;   // 4 waves x 32 rows
#pragma unroll
  for (int j = 0; j < 8; ++j) {
    float s = bs[j]; int i_ = bi[j];
#pragma unroll
    for (int m = 1; m <= 8; m <<= 1) {
      float s2 = __shfl_xor(s, m);
      int   i2 = __shfl_xor(i_, m);
      if (s2 < s || (s2 == s && i2 < i_)) { s = s2; i_ = i2; }
    }
    if (l15 == 0) {
      int row32 = ((j >> 2) << 4) + (quad << 2) + (j & 3);   // rt*16 + quad*4 + rr
      unsigned u = __float_as_uint(s);
      u = (u & 0x80000000u) ? ~u : (u | 0x80000000u);        // order-preserving map
      red[wave * 32 + row32] = ((unsigned long long)u << 32) | (unsigned)i_;
    }
  }
  __syncthreads();
  // waves (wh) and (wh+2) cover the same 32 pixel rows with disjoint codes
  if (wave == 0) {
    int wh2 = lane >> 5, r31 = lane & 31;
    unsigned long long a = red[wh2 * 32 + r31];
    unsigned long long b = red[(wh2 + 2) * 32 + r31];
    if (b < a) a = b;
    atomicMin(&best[p0 + lane], a);
  }
}

// ---------------- K3: gather quantized, write codes, accumulate loss ----------------
__global__ void k_gather(const float* __restrict__ z, const float* __restrict__ cb,
                         const unsigned long long* __restrict__ best,
                         float* __restrict__ out_codes, float* __restrict__ out_q,
                         float* __restrict__ lossac) {
  int b  = blockIdx.x >> 4;
  int cg = blockIdx.x & 15;
  int t  = threadIdx.x;
  int idx[4];
#pragma unroll
  for (int pi = 0; pi < 4; ++pi) {
    int p = t + pi * 256;
    unsigned long long pk = best[b * 1024 + p];
    idx[pi] = (int)(unsigned)(pk & 0xffffffffu);
    if (cg == 0) out_codes[b * 1024 + p] = (float)idx[pi];
  }
  float lsum = 0.0f;
#pragma unroll
  for (int ci = 0; ci < 16; ++ci) {
    int c = cg * 16 + ci;
#pragma unroll
    for (int pi = 0; pi < 4; ++pi) {
      int p = t + pi * 256;
      float q  = cb[(size_t)idx[pi] * CDIM + c];
      size_t o = ((size_t)(b * CDIM + c)) * 1024 + p;
      float zv = z[o];
      float d  = q - zv;
      out_q[o] = zv + d;                 // straight-through: same op order as reference
      lsum = fmaf(d, d, lsum);
    }
  }
#pragma unroll
  for (int m = 32; m >= 1; m >>= 1) lsum += __shfl_xor(lsum, m);
  __shared__ float wsum[4];
  if ((t & 63) == 0) wsum[t >> 6] = lsum;
  __syncthreads();
  if (t == 0) atomicAdd(lossac, wsum[0] + wsum[1] + wsum[2] + wsum[3]);
}

// ---------------- K4: finalize loss scalar ----------------
__global__ void k_final(const float* __restrict__ lossac, float* __restrict__ out_loss) {
  if (threadIdx.x == 0) out_loss[0] = lossac[0] * (1.25f / 4194304.0f);
}

extern "C" void kernel_launch(void* const* d_in, const int* in_sizes, int n_in,
                              void* d_out, int out_size, void* d_ws, size_t ws_size,
                              hipStream_t stream) {
  (void)in_sizes; (void)n_in; (void)out_size; (void)ws_size;
  const float* z  = (const float*)d_in[0];
  const float* cb = (const float*)d_in[1];
  float* outf = (float*)d_out;

  char* ws = (char*)d_ws;
  f16*   bfh  = (f16*)ws;                                   // 4 MB packed B-frag hi
  f16*   bfl  = (f16*)(ws + (4 << 20));                     // 4 MB packed B-frag lo
  float* esq  = (float*)(ws + (8 << 20));                   // 32 KB
  unsigned long long* best = (unsigned long long*)(ws + (8 << 20) + 32768);  // 128 KB
  float* lossac = (float*)(ws + (8 << 20) + 32768 + 131072);                 // 4 B (pad 256)
  float* zsq    = (float*)(ws + (8 << 20) + 32768 + 131072 + 256);           // 64 KB
  int*   cnt    = (int*)  (ws + (8 << 20) + 32768 + 131072 + 256 + 65536);   // 32 B

  // scratch inside d_out's quantized region (overwritten by k_gather afterwards)
  f16* zhi = (f16*)(outf + 16384);                          // 8 MB
  f16* zlo = zhi + (size_t)NPIX * CDIM;                     // 8 MB

  hipMemsetAsync(best, 0xFF, (size_t)NPIX * 8, stream);
  hipMemsetAsync(lossac, 0, 4, stream);
  hipMemsetAsync(cnt, 0, 32, stream);

  k_prep   <<<608,  256, 0,     stream>>>(z, cb, zhi, zlo, zsq, bfh, bfl, esq);
  k_score  <<<2048, 256, 65536, stream>>>(bfh, bfl, zhi, zlo, esq, zsq, cnt, best);
  k_gather <<<256,  256, 0,     stream>>>(z, cb, best, outf, outf + 16384, lossac);
  k_final  <<<1,    64,  0,     stream>>>(lossac, outf + 16384 + (size_t)NPIX * CDIM);
}

// Round 8
// 349.702 us; speedup vs baseline: 1.3372x; 1.3372x over previous
//
#include <hip/hip_runtime.h>

// VQ-VAE vector quantizer, MI355X (gfx950)
// B=16, C=256, H=W=32 -> N=16384 pixels; K=8192 codes.
// R11: R7/R9/R10 triangulation: three different structures all land
// 345-382us at ~23% MfmaUtil -> common limiter is PER-ITER exposed L2
// latency on the B stream (2MB/block, not L1-resident; compute/iter
// ~230cyc < latency ~300cyc; compiler does NO cross-iter software
// pipelining under unroll 1). Fix: manual 1-iter-deep B double-buffer in
// registers (B0[16]/B1[16], 64+64 regs): issue iter i+1's 16 loads
// BEFORE computing iter i -> compiler emits counted vmcnt(16), giving a
// full iteration (~900cyc across 2 waves) of latency cover. To afford
// 128 B-regs, A returns to LDS (R7's in-loop swizzled ds_reads; LDS pipe
// otherwise idle, overlaps under MFMA+vmem). NO waves_per_eu attribute
// (arch demand must exceed 128): unified ~210 -> 2 waves/SIMD.
// All B0/B1 indices compile-time after unroll (rule: runtime-indexed
// arrays go to scratch). Last-iter prefetch clamps to 31 (one redundant
// load, uniform control flow). Numerics bit-identical to R7/R10: same
// 8-step cs MFMA chain per code, same epilogue rounding, monotone k,
// index-ordered ties.
// Canaries: k_score WRITE_SIZE ~1MB (scratch spill), FETCH ~85MB.

typedef _Float16 f16;
typedef __attribute__((ext_vector_type(8))) _Float16 f16x8;
typedef __attribute__((ext_vector_type(4))) float f32x4;

#define NPIX   16384      // B*H*W
#define CDIM   256
#define KCODE  8192

// ---------------- K0: fused prep ----------------
// bid <  512 : codebook -> packed MFMA B-fragments (hi/lo limbs, x8192)
// bid <  576 : z -> zhi/zlo fp16 limbs + z_sq (bit-exact pairwise)
// bid <  608 : e_sq (bit-exact numpy pairwise, thread per row)
__global__ void k_prep(const float* __restrict__ z, const float* __restrict__ cb,
                       f16* __restrict__ zhi, f16* __restrict__ zlo,
                       float* __restrict__ zsq,
                       f16* __restrict__ bfh, f16* __restrict__ bfl,
                       float* __restrict__ esq) {
  int bid = blockIdx.x;
  int t   = threadIdx.x;
  if (bid < 512) {
    // ---- cbsplit: bf[((kb*8+cs)*64+lane)*8+j] =
    //      limb(cb[kb*16+(lane&15)][cs*32+((lane>>4)&3)*8+j]) ----
    int kb = bid;
#pragma unroll
    for (int half = 0; half < 2; ++half) {
      int o    = half * 256 + t;         // o = cs*64 + lane, 0..511
      int lane = o & 63;
      int cs   = o >> 6;
      int code = kb * 16 + (lane & 15);
      int c0   = cs * 32 + ((lane >> 4) & 3) * 8;
      const float* src = cb + (size_t)code * CDIM + c0;
      float4 v0 = *(const float4*)(src);
      float4 v1 = *(const float4*)(src + 4);
      float e[8] = {v0.x, v0.y, v0.z, v0.w, v1.x, v1.y, v1.z, v1.w};
      f16x8 h8, l8;
#pragma unroll
      for (int j = 0; j < 8; ++j) {
        float ej = e[j] * 8192.0f;
        f16 h = (f16)ej;
        h8[j] = h;
        l8[j] = (f16)((ej - (float)h) * 4096.0f);
      }
      size_t off = ((size_t)kb * 512 + o) * 8;
      *(f16x8*)(bfh + off) = h8;
      *(f16x8*)(bfl + off) = l8;
    }
  } else if (bid < 576) {
    // ---- zprep: limbs + zsq (numpy pairwise fp32 order, contract off) ----
#pragma clang fp contract(off)
    int n = (bid - 512) * 256 + t;
    int b = n >> 10, p = n & 1023;
    const float* src = z + (size_t)b * CDIM * 1024 + p;
    f16* dh = zhi + (size_t)n * CDIM;
    f16* dl = zlo + (size_t)n * CDIM;
    float half_[2];
    for (int m = 0; m < 2; ++m) {
      float r[8];
#pragma unroll
      for (int j = 0; j < 8; ++j) r[j] = 0.0f;
      for (int i = 0; i < 16; ++i) {
        f16x8 h8, l8;
#pragma unroll
        for (int j = 0; j < 8; ++j) {
          float v = src[(size_t)(m * 128 + i * 8 + j) * 1024];  // coalesced
          r[j] = r[j] + v * v;                                  // mul then add
          f16 h = (f16)v;
          h8[j] = h;
          l8[j] = (f16)((v - (float)h) * 4096.0f);              // scaled low limb
        }
        *(f16x8*)(dh + m * 128 + i * 8) = h8;
        *(f16x8*)(dl + m * 128 + i * 8) = l8;
      }
      half_[m] = ((r[0] + r[1]) + (r[2] + r[3])) + ((r[4] + r[5]) + (r[6] + r[7]));
    }
    zsq[n] = half_[0] + half_[1];
  } else {
    // ---- esq: bit-exact numpy pairwise ----
#pragma clang fp contract(off)
    int row = (bid - 576) * 256 + t;
    const float* src = cb + (size_t)row * CDIM;
    float half_[2];
    for (int m = 0; m < 2; ++m) {
      float r[8];
#pragma unroll
      for (int j = 0; j < 8; ++j) r[j] = 0.0f;
      for (int i = 0; i < 16; ++i) {
        float4 v0 = *(const float4*)(src + m * 128 + i * 8);
        float4 v1 = *(const float4*)(src + m * 128 + i * 8 + 4);
        r[0] = r[0] + v0.x * v0.x;  r[1] = r[1] + v0.y * v0.y;
        r[2] = r[2] + v0.z * v0.z;  r[3] = r[3] + v0.w * v0.w;
        r[4] = r[4] + v1.x * v1.x;  r[5] = r[5] + v1.y * v1.y;
        r[6] = r[6] + v1.z * v1.z;  r[7] = r[7] + v1.w * v1.w;
      }
      half_[m] = ((r[0] + r[1]) + (r[2] + r[3])) + ((r[4] + r[5]) + (r[6] + r[7]));
    }
    esq[row] = half_[0] + half_[1];
  }
}

// ---------------- K2: fused score GEMM + argmin ----------------
// 2048 blocks x 256 threads (4 waves = 2 wh x 2 wk). Job = (kslice, ptile)
// claimed at runtime: kslice = this block's actual XCD id (1 MB hi+lo
// packed codebook slice stays L2-resident per XCD), ptile = per-slice
// ticket. Pigeonhole: a block seeing all 8 counters >= 256 implies 2048
// claims by others -- impossible with 2048 blocks each claiming <= 1.
// A-tile 64px x 256c hi+lo in 64KB LDS (16B xor swizzle), read per-cs
// (R7 pattern). B double-buffered one full iteration ahead in registers
// (B0/B1, 16 f16x8 each) -> counted vmcnt, L2 latency hidden.
// Wave (wh,wk): 32px x 16 codes/iter, 32 iters.
#define LOADB(Bset, it) do {                                                  \
    int kbq_ = kslice * 64 + (it) * 2 + wk;                                   \
    size_t base_ = (size_t)kbq_ * 4096 + (size_t)lane * 8;                    \
    _Pragma("unroll")                                                         \
    for (int cs_ = 0; cs_ < 8; ++cs_) {                                       \
      Bset[2*cs_]   = *(const f16x8*)(bfh + base_ + (size_t)cs_ * 512);       \
      Bset[2*cs_+1] = *(const f16x8*)(bfl + base_ + (size_t)cs_ * 512);       \
    } } while (0)

#define COMPUTE(Bset, it) do {                                                \
    int kbase_ = kslice * 1024 + (it) * 32 + wk * 16;                         \
    f32x4 hh[2], mx[2];                                                       \
    _Pragma("unroll")                                                         \
    for (int rt = 0; rt < 2; ++rt) { hh[rt] = vzero; mx[rt] = vzero; }        \
    _Pragma("unroll")                                                         \
    for (int cs = 0; cs < 8; ++cs) {                                          \
      f16x8 ah[2], al[2];                                                     \
      _Pragma("unroll")                                                       \
      for (int rt = 0; rt < 2; ++rt) {                                        \
        int px = wh * 32 + rt * 16 + l15;                                     \
        int sb = (cs * 4 + quad) ^ (px & 7);                                  \
        int eo = px * 256 + sb * 8;          /* f16 units */                  \
        ah[rt] = *(const f16x8*)(sAh + eo);                                   \
        al[rt] = *(const f16x8*)(sAl + eo);                                   \
      }                                                                       \
      _Pragma("unroll")                                                       \
      for (int rt = 0; rt < 2; ++rt) {                                        \
        hh[rt] = __builtin_amdgcn_mfma_f32_16x16x32_f16(ah[rt], Bset[2*cs],   hh[rt], 0, 0, 0); \
        mx[rt] = __builtin_amdgcn_mfma_f32_16x16x32_f16(ah[rt], Bset[2*cs+1], mx[rt], 0, 0, 0); \
        mx[rt] = __builtin_amdgcn_mfma_f32_16x16x32_f16(al[rt], Bset[2*cs],   mx[rt], 0, 0, 0); \
      }                                                                       \
    }                                                                         \
    {                                                                         \
      int k = kbase_ + l15;                                                   \
      float es = esq[k];                                                      \
      _Pragma("unroll")                                                       \
      for (int rt = 0; rt < 2; ++rt)                                          \
        _Pragma("unroll")                                                     \
        for (int rr = 0; rr < 4; ++rr) {                                      \
          float v = hh[rt][rr] * 2.44140625e-4f;                   /* exact */\
          float w = fmaf(mx[rt][rr], 5.9604644775390625e-8f, v);              \
          float d = (Zr[rt * 4 + rr] - w) + es;                               \
          int j = rt * 4 + rr;                                                \
          if (d < bs[j]) { bs[j] = d; bi[j] = k; }                            \
        }                                                                     \
    } } while (0)

__launch_bounds__(256)
__global__ void k_score(const f16* __restrict__ bfh, const f16* __restrict__ bfl,
                        const f16* __restrict__ zhi, const f16* __restrict__ zlo,
                        const float* __restrict__ esq, const float* __restrict__ zsq,
                        int* __restrict__ cnt,
                        unsigned long long* __restrict__ best) {
  extern __shared__ char smem[];
  f16* sAh = (f16*)smem;               // 32 KB
  f16* sAl = (f16*)(smem + 32768);     // 32 KB
  int t = threadIdx.x;
  int wave = t >> 6, lane = t & 63;
  int quad = lane >> 4, l15 = lane & 15;
  int wh = wave & 1;                   // pixel half: rows [wh*32, wh*32+32)
  int wk = wave >> 1;                  // code strip 0..1

  // ---- claim (kslice, ptile) aligned to the real XCD ----
  __shared__ int s_job[2];
  if (t == 0) {
    unsigned xcc;
    asm volatile("s_getreg_b32 %0, hwreg(HW_REG_XCC_ID)" : "=s"(xcc));
    int x = (int)(xcc & 7u);
    int pt = -1, ks = 0;
    for (int trial = 0; trial < 16 && pt < 0; ++trial) {
      int j = (x + trial) & 7;
      int tk = atomicAdd(&cnt[j], 1);
      if (tk < 256) { pt = tk; ks = j; }
    }
    if (pt < 0) pt = 0;                // unreachable (see proof above)
    s_job[0] = pt; s_job[1] = ks;
  }
  __syncthreads();
  int ptile  = s_job[0];
  int kslice = s_job[1];
  int p0 = ptile * 64;

  // ---- stage A-tile (hi & lo), xor-swizzled at 16B granularity ----
  {
    int r = t >> 2, seg = t & 3;
    const uint4* gh = (const uint4*)zhi + ((size_t)(p0 + r)) * 32;
    const uint4* gl = (const uint4*)zlo + ((size_t)(p0 + r)) * 32;
    uint4* sh = (uint4*)sAh + r * 32;
    uint4* sl = (uint4*)sAl + r * 32;
#pragma unroll
    for (int j = 0; j < 8; ++j) {
      int blk = seg * 8 + j;
      int sb = blk ^ (r & 7);
      sh[sb] = gh[blk];
      sl[sb] = gl[blk];
    }
  }

  // Z for my 8 pixel rows (C/D layout: row = quad*4 + reg)
  float Zr[8];
#pragma unroll
  for (int rt = 0; rt < 2; ++rt)
#pragma unroll
    for (int rr = 0; rr < 4; ++rr)
      Zr[rt * 4 + rr] = zsq[p0 + wh * 32 + rt * 16 + quad * 4 + rr];

  __syncthreads();

  float bs[8];
  int   bi[8];
#pragma unroll
  for (int j = 0; j < 8; ++j) { bs[j] = 3.0e38f; bi[j] = 0; }

  const f32x4 vzero = {0.0f, 0.0f, 0.0f, 0.0f};

  // ---- software-pipelined main loop: prefetch iter i+1 before compute i ----
  f16x8 B0[16], B1[16];
  LOADB(B0, 0);
#pragma unroll 1
  for (int tt = 0; tt < 16; ++tt) {
    int i0 = tt * 2, i1 = tt * 2 + 1;
    LOADB(B1, i1);
    COMPUTE(B0, i0);
    int inext = (i1 + 1 < 32) ? i1 + 1 : 31;   // clamp: one redundant reload at end
    LOADB(B0, inext);
    COMPUTE(B1, i1);
  }

  // ---- reduce: 16 lanes of each quad -> LDS -> across waves ----
  __syncthreads();                          // A-tile dead; reuse LDS
  unsigned long long* red = (unsigned long long*)smem;   // 4 waves x 32 rows
#pragma unroll
  for (int j = 0; j < 8; ++j) {
    float s = bs[j]; int i_ = bi[j];
#pragma unroll
    for (int m = 1; m <= 8; m <<= 1) {
      float s2 = __shfl_xor(s, m);
      int   i2 = __shfl_xor(i_, m);
      if (s2 < s || (s2 == s && i2 < i_)) { s = s2; i_ = i2; }
    }
    if (l15 == 0) {
      int row32 = ((j >> 2) << 4) + (quad << 2) + (j & 3);   // rt*16 + quad*4 + rr
      unsigned u = __float_as_uint(s);
      u = (u & 0x80000000u) ? ~u : (u | 0x80000000u);        // order-preserving map
      red[wave * 32 + row32] = ((unsigned long long)u << 32) | (unsigned)i_;
    }
  }
  __syncthreads();
  // waves (wh) and (wh+2) cover the same 32 pixel rows with disjoint codes
  if (wave == 0) {
    int wh2 = lane >> 5, r31 = lane & 31;
    unsigned long long a = red[wh2 * 32 + r31];
    unsigned long long b = red[(wh2 + 2) * 32 + r31];
    if (b < a) a = b;
    atomicMin(&best[p0 + lane], a);
  }
}

// ---------------- K3: gather quantized, write codes, accumulate loss ----------------
__global__ void k_gather(const float* __restrict__ z, const float* __restrict__ cb,
                         const unsigned long long* __restrict__ best,
                         float* __restrict__ out_codes, float* __restrict__ out_q,
                         float* __restrict__ lossac) {
  int b  = blockIdx.x >> 4;
  int cg = blockIdx.x & 15;
  int t  = threadIdx.x;
  int idx[4];
#pragma unroll
  for (int pi = 0; pi < 4; ++pi) {
    int p = t + pi * 256;
    unsigned long long pk = best[b * 1024 + p];
    idx[pi] = (int)(unsigned)(pk & 0xffffffffu);
    if (cg == 0) out_codes[b * 1024 + p] = (float)idx[pi];
  }
  float lsum = 0.0f;
#pragma unroll
  for (int ci = 0; ci < 16; ++ci) {
    int c = cg * 16 + ci;
#pragma unroll
    for (int pi = 0; pi < 4; ++pi) {
      int p = t + pi * 256;
      float q  = cb[(size_t)idx[pi] * CDIM + c];
      size_t o = ((size_t)(b * CDIM + c)) * 1024 + p;
      float zv = z[o];
      float d  = q - zv;
      out_q[o] = zv + d;                 // straight-through: same op order as reference
      lsum = fmaf(d, d, lsum);
    }
  }
#pragma unroll
  for (int m = 32; m >= 1; m >>= 1) lsum += __shfl_xor(lsum, m);
  __shared__ float wsum[4];
  if ((t & 63) == 0) wsum[t >> 6] = lsum;
  __syncthreads();
  if (t == 0) atomicAdd(lossac, wsum[0] + wsum[1] + wsum[2] + wsum[3]);
}

// ---------------- K4: finalize loss scalar ----------------
__global__ void k_final(const float* __restrict__ lossac, float* __restrict__ out_loss) {
  if (threadIdx.x == 0) out_loss[0] = lossac[0] * (1.25f / 4194304.0f);
}

extern "C" void kernel_launch(void* const* d_in, const int* in_sizes, int n_in,
                              void* d_out, int out_size, void* d_ws, size_t ws_size,
                              hipStream_t stream) {
  (void)in_sizes; (void)n_in; (void)out_size; (void)ws_size;
  const float* z  = (const float*)d_in[0];
  const float* cb = (const float*)d_in[1];
  float* outf = (float*)d_out;

  char* ws = (char*)d_ws;
  f16*   bfh  = (f16*)ws;                                   // 4 MB packed B-frag hi
  f16*   bfl  = (f16*)(ws + (4 << 20));                     // 4 MB packed B-frag lo
  float* esq  = (float*)(ws + (8 << 20));                   // 32 KB
  unsigned long long* best = (unsigned long long*)(ws + (8 << 20) + 32768);  // 128 KB
  float* lossac = (float*)(ws + (8 << 20) + 32768 + 131072);                 // 4 B (pad 256)
  float* zsq    = (float*)(ws + (8 << 20) + 32768 + 131072 + 256);           // 64 KB
  int*   cnt    = (int*)  (ws + (8 << 20) + 32768 + 131072 + 256 + 65536);   // 32 B

  // scratch inside d_out's quantized region (overwritten by k_gather afterwards)
  f16* zhi = (f16*)(outf + 16384);                          // 8 MB
  f16* zlo = zhi + (size_t)NPIX * CDIM;                     // 8 MB

  hipMemsetAsync(best, 0xFF, (size_t)NPIX * 8, stream);
  hipMemsetAsync(lossac, 0, 4, stream);
  hipMemsetAsync(cnt, 0, 32, stream);

  k_prep   <<<608,  256, 0,     stream>>>(z, cb, zhi, zlo, zsq, bfh, bfl, esq);
  k_score  <<<2048, 256, 65536, stream>>>(bfh, bfl, zhi, zlo, esq, zsq, cnt, best);
  k_gather <<<256,  256, 0,     stream>>>(z, cb, best, outf, outf + 16384, lossac);
  k_final  <<<1,    64,  0,     stream>>>(lossac, outf + 16384 + (size_t)NPIX * CDIM);
}

// Round 9
// 345.871 us; speedup vs baseline: 1.3520x; 1.0111x over previous
//
#include <hip/hip_runtime.h>

// VQ-VAE vector quantizer, MI355X (gfx950)
// B=16, C=256, H=W=32 -> N=16384 pixels; K=8192 codes.
// R12: R11 (B reg-dbuf + counted vmcnt) hit 256us, MfmaUtil 35%. Per-CU
// pipe audit: MFMA 238k cyc (99us), LDS A-re-read 286k (119us, 32MB),
// B vmem 262k (109us, 16MB) -- LDS is now the tallest pipe. Cut it in
// half: hoist rt=0's A fragments (16 f16x8 = 64 VGPR) to registers in
// the prologue (same swizzled addresses, read ONCE); rt=1 stays on the
// per-iter LDS path. Register budget: R11's proven 128 + 64 = ~192 < 256
// -> 2 waves/SIMD preserved. Per-accumulator MFMA chains keep identical
// cs order -> bit-identical numerics (same epilogue rounding, monotone k,
// index-ordered ties). Also folded the 3 hipMemsetAsync into a 609th
// k_prep block (fewer dispatches).
// Canaries: k_score WRITE_SIZE ~1MB (spill); OccupancyPercent ~22%
// (if ~11.5%, regalloc ballooned past 256 -> revert A-hoist).

typedef _Float16 f16;
typedef __attribute__((ext_vector_type(8))) _Float16 f16x8;
typedef __attribute__((ext_vector_type(4))) float f32x4;

#define NPIX   16384      // B*H*W
#define CDIM   256
#define KCODE  8192

// ---------------- K0: fused prep ----------------
// bid <  512 : codebook -> packed MFMA B-fragments (hi/lo limbs, x8192)
// bid <  576 : z -> zhi/zlo fp16 limbs + z_sq (bit-exact pairwise)
// bid <  608 : e_sq (bit-exact numpy pairwise, thread per row)
// bid == 608 : init best/lossac/cnt (replaces 3 hipMemsetAsync)
__global__ void k_prep(const float* __restrict__ z, const float* __restrict__ cb,
                       f16* __restrict__ zhi, f16* __restrict__ zlo,
                       float* __restrict__ zsq,
                       f16* __restrict__ bfh, f16* __restrict__ bfl,
                       float* __restrict__ esq,
                       unsigned long long* __restrict__ best,
                       float* __restrict__ lossac, int* __restrict__ cnt) {
  int bid = blockIdx.x;
  int t   = threadIdx.x;
  if (bid < 512) {
    // ---- cbsplit: bf[((kb*8+cs)*64+lane)*8+j] =
    //      limb(cb[kb*16+(lane&15)][cs*32+((lane>>4)&3)*8+j]) ----
    int kb = bid;
#pragma unroll
    for (int half = 0; half < 2; ++half) {
      int o    = half * 256 + t;         // o = cs*64 + lane, 0..511
      int lane = o & 63;
      int cs   = o >> 6;
      int code = kb * 16 + (lane & 15);
      int c0   = cs * 32 + ((lane >> 4) & 3) * 8;
      const float* src = cb + (size_t)code * CDIM + c0;
      float4 v0 = *(const float4*)(src);
      float4 v1 = *(const float4*)(src + 4);
      float e[8] = {v0.x, v0.y, v0.z, v0.w, v1.x, v1.y, v1.z, v1.w};
      f16x8 h8, l8;
#pragma unroll
      for (int j = 0; j < 8; ++j) {
        float ej = e[j] * 8192.0f;
        f16 h = (f16)ej;
        h8[j] = h;
        l8[j] = (f16)((ej - (float)h) * 4096.0f);
      }
      size_t off = ((size_t)kb * 512 + o) * 8;
      *(f16x8*)(bfh + off) = h8;
      *(f16x8*)(bfl + off) = l8;
    }
  } else if (bid < 576) {
    // ---- zprep: limbs + zsq (numpy pairwise fp32 order, contract off) ----
#pragma clang fp contract(off)
    int n = (bid - 512) * 256 + t;
    int b = n >> 10, p = n & 1023;
    const float* src = z + (size_t)b * CDIM * 1024 + p;
    f16* dh = zhi + (size_t)n * CDIM;
    f16* dl = zlo + (size_t)n * CDIM;
    float half_[2];
    for (int m = 0; m < 2; ++m) {
      float r[8];
#pragma unroll
      for (int j = 0; j < 8; ++j) r[j] = 0.0f;
      for (int i = 0; i < 16; ++i) {
        f16x8 h8, l8;
#pragma unroll
        for (int j = 0; j < 8; ++j) {
          float v = src[(size_t)(m * 128 + i * 8 + j) * 1024];  // coalesced
          r[j] = r[j] + v * v;                                  // mul then add
          f16 h = (f16)v;
          h8[j] = h;
          l8[j] = (f16)((v - (float)h) * 4096.0f);              // scaled low limb
        }
        *(f16x8*)(dh + m * 128 + i * 8) = h8;
        *(f16x8*)(dl + m * 128 + i * 8) = l8;
      }
      half_[m] = ((r[0] + r[1]) + (r[2] + r[3])) + ((r[4] + r[5]) + (r[6] + r[7]));
    }
    zsq[n] = half_[0] + half_[1];
  } else if (bid < 608) {
    // ---- esq: bit-exact numpy pairwise ----
#pragma clang fp contract(off)
    int row = (bid - 576) * 256 + t;
    const float* src = cb + (size_t)row * CDIM;
    float half_[2];
    for (int m = 0; m < 2; ++m) {
      float r[8];
#pragma unroll
      for (int j = 0; j < 8; ++j) r[j] = 0.0f;
      for (int i = 0; i < 16; ++i) {
        float4 v0 = *(const float4*)(src + m * 128 + i * 8);
        float4 v1 = *(const float4*)(src + m * 128 + i * 8 + 4);
        r[0] = r[0] + v0.x * v0.x;  r[1] = r[1] + v0.y * v0.y;
        r[2] = r[2] + v0.z * v0.z;  r[3] = r[3] + v0.w * v0.w;
        r[4] = r[4] + v1.x * v1.x;  r[5] = r[5] + v1.y * v1.y;
        r[6] = r[6] + v1.z * v1.z;  r[7] = r[7] + v1.w * v1.w;
      }
      half_[m] = ((r[0] + r[1]) + (r[2] + r[3])) + ((r[4] + r[5]) + (r[6] + r[7]));
    }
    esq[row] = half_[0] + half_[1];
  } else {
    // ---- init: best = 0xFF.., lossac = 0, cnt[8] = 0 ----
#pragma unroll 4
    for (int i = 0; i < 64; ++i)
      best[(size_t)i * 256 + t] = ~0ull;
    if (t == 0) *lossac = 0.0f;
    if (t < 8) cnt[t] = 0;
  }
}

// ---------------- K2: fused score GEMM + argmin ----------------
// 2048 blocks x 256 threads (4 waves = 2 wh x 2 wk). Job = (kslice, ptile)
// claimed at runtime: kslice = this block's actual XCD id (1 MB hi+lo
// packed codebook slice stays L2-resident per XCD), ptile = per-slice
// ticket. Pigeonhole: a block seeing all 8 counters >= 256 implies 2048
// claims by others -- impossible with 2048 blocks each claiming <= 1.
// A-tile 64px x 256c hi+lo in 64KB LDS (16B xor swizzle): rt=0 fragments
// hoisted to regs in the prologue (read once), rt=1 read per-cs per-iter.
// B double-buffered one full iteration ahead in registers (B0/B1) ->
// counted vmcnt, L2 latency hidden. Wave (wh,wk): 32px x 16 codes/iter,
// 32 iters.
#define LOADB(Bset, it) do {                                                  \
    int kbq_ = kslice * 64 + (it) * 2 + wk;                                   \
    size_t base_ = (size_t)kbq_ * 4096 + (size_t)lane * 8;                    \
    _Pragma("unroll")                                                         \
    for (int cs_ = 0; cs_ < 8; ++cs_) {                                       \
      Bset[2*cs_]   = *(const f16x8*)(bfh + base_ + (size_t)cs_ * 512);       \
      Bset[2*cs_+1] = *(const f16x8*)(bfl + base_ + (size_t)cs_ * 512);       \
    } } while (0)

#define COMPUTE(Bset, it) do {                                                \
    int kbase_ = kslice * 1024 + (it) * 32 + wk * 16;                         \
    f32x4 hh[2], mx[2];                                                       \
    _Pragma("unroll")                                                         \
    for (int rt = 0; rt < 2; ++rt) { hh[rt] = vzero; mx[rt] = vzero; }        \
    _Pragma("unroll")                                                         \
    for (int cs = 0; cs < 8; ++cs) {                                          \
      f16x8 ah1, al1;                                                         \
      {                                                                       \
        int px = wh * 32 + 16 + l15;                                          \
        int sb = (cs * 4 + quad) ^ (px & 7);                                  \
        int eo = px * 256 + sb * 8;          /* f16 units */                  \
        ah1 = *(const f16x8*)(sAh + eo);                                      \
        al1 = *(const f16x8*)(sAl + eo);                                      \
      }                                                                       \
      hh[0] = __builtin_amdgcn_mfma_f32_16x16x32_f16(aA0[2*cs],   Bset[2*cs],   hh[0], 0, 0, 0); \
      mx[0] = __builtin_amdgcn_mfma_f32_16x16x32_f16(aA0[2*cs],   Bset[2*cs+1], mx[0], 0, 0, 0); \
      mx[0] = __builtin_amdgcn_mfma_f32_16x16x32_f16(aA0[2*cs+1], Bset[2*cs],   mx[0], 0, 0, 0); \
      hh[1] = __builtin_amdgcn_mfma_f32_16x16x32_f16(ah1,         Bset[2*cs],   hh[1], 0, 0, 0); \
      mx[1] = __builtin_amdgcn_mfma_f32_16x16x32_f16(ah1,         Bset[2*cs+1], mx[1], 0, 0, 0); \
      mx[1] = __builtin_amdgcn_mfma_f32_16x16x32_f16(al1,         Bset[2*cs],   mx[1], 0, 0, 0); \
    }                                                                         \
    {                                                                         \
      int k = kbase_ + l15;                                                   \
      float es = esq[k];                                                      \
      _Pragma("unroll")                                                       \
      for (int rt = 0; rt < 2; ++rt)                                          \
        _Pragma("unroll")                                                     \
        for (int rr = 0; rr < 4; ++rr) {                                      \
          float v = hh[rt][rr] * 2.44140625e-4f;                   /* exact */\
          float w = fmaf(mx[rt][rr], 5.9604644775390625e-8f, v);              \
          float d = (Zr[rt * 4 + rr] - w) + es;                               \
          int j = rt * 4 + rr;                                                \
          if (d < bs[j]) { bs[j] = d; bi[j] = k; }                            \
        }                                                                     \
    } } while (0)

__launch_bounds__(256)
__global__ void k_score(const f16* __restrict__ bfh, const f16* __restrict__ bfl,
                        const f16* __restrict__ zhi, const f16* __restrict__ zlo,
                        const float* __restrict__ esq, const float* __restrict__ zsq,
                        int* __restrict__ cnt,
                        unsigned long long* __restrict__ best) {
  extern __shared__ char smem[];
  f16* sAh = (f16*)smem;               // 32 KB
  f16* sAl = (f16*)(smem + 32768);     // 32 KB
  int t = threadIdx.x;
  int wave = t >> 6, lane = t & 63;
  int quad = lane >> 4, l15 = lane & 15;
  int wh = wave & 1;                   // pixel half: rows [wh*32, wh*32+32)
  int wk = wave >> 1;                  // code strip 0..1

  // ---- claim (kslice, ptile) aligned to the real XCD ----
  __shared__ int s_job[2];
  if (t == 0) {
    unsigned xcc;
    asm volatile("s_getreg_b32 %0, hwreg(HW_REG_XCC_ID)" : "=s"(xcc));
    int x = (int)(xcc & 7u);
    int pt = -1, ks = 0;
    for (int trial = 0; trial < 16 && pt < 0; ++trial) {
      int j = (x + trial) & 7;
      int tk = atomicAdd(&cnt[j], 1);
      if (tk < 256) { pt = tk; ks = j; }
    }
    if (pt < 0) pt = 0;                // unreachable (see proof above)
    s_job[0] = pt; s_job[1] = ks;
  }
  __syncthreads();
  int ptile  = s_job[0];
  int kslice = s_job[1];
  int p0 = ptile * 64;

  // ---- stage A-tile (hi & lo), xor-swizzled at 16B granularity ----
  {
    int r = t >> 2, seg = t & 3;
    const uint4* gh = (const uint4*)zhi + ((size_t)(p0 + r)) * 32;
    const uint4* gl = (const uint4*)zlo + ((size_t)(p0 + r)) * 32;
    uint4* sh = (uint4*)sAh + r * 32;
    uint4* sl = (uint4*)sAl + r * 32;
#pragma unroll
    for (int j = 0; j < 8; ++j) {
      int blk = seg * 8 + j;
      int sb = blk ^ (r & 7);
      sh[sb] = gh[blk];
      sl[sb] = gl[blk];
    }
  }

  // Z for my 8 pixel rows (C/D layout: row = quad*4 + reg)
  float Zr[8];
#pragma unroll
  for (int rt = 0; rt < 2; ++rt)
#pragma unroll
    for (int rr = 0; rr < 4; ++rr)
      Zr[rt * 4 + rr] = zsq[p0 + wh * 32 + rt * 16 + quad * 4 + rr];

  __syncthreads();

  // ---- prologue: hoist rt=0's A fragments to registers (read once) ----
  f16x8 aA0[16];                       // [cs*2 + limb], 64 VGPRs
#pragma unroll
  for (int cs = 0; cs < 8; ++cs) {
    int px = wh * 32 + l15;            // rt = 0
    int sb = (cs * 4 + quad) ^ (px & 7);
    int eo = px * 256 + sb * 8;        // f16 units
    aA0[2*cs]   = *(const f16x8*)(sAh + eo);
    aA0[2*cs+1] = *(const f16x8*)(sAl + eo);
  }

  float bs[8];
  int   bi[8];
#pragma unroll
  for (int j = 0; j < 8; ++j) { bs[j] = 3.0e38f; bi[j] = 0; }

  const f32x4 vzero = {0.0f, 0.0f, 0.0f, 0.0f};

  // ---- software-pipelined main loop: prefetch iter i+1 before compute i ----
  f16x8 B0[16], B1[16];
  LOADB(B0, 0);
#pragma unroll 1
  for (int tt = 0; tt < 16; ++tt) {
    int i0 = tt * 2, i1 = tt * 2 + 1;
    LOADB(B1, i1);
    COMPUTE(B0, i0);
    int inext = (i1 + 1 < 32) ? i1 + 1 : 31;   // clamp: one redundant reload at end
    LOADB(B0, inext);
    COMPUTE(B1, i1);
  }

  // ---- reduce: 16 lanes of each quad -> LDS -> across waves ----
  __syncthreads();                          // A-tile dead; reuse LDS
  unsigned long long* red = (unsigned long long*)smem;   // 4 waves x 32 rows
#pragma unroll
  for (int j = 0; j < 8; ++j) {
    float s = bs[j]; int i_ = bi[j];
#pragma unroll
    for (int m = 1; m <= 8; m <<= 1) {
      float s2 = __shfl_xor(s, m);
      int   i2 = __shfl_xor(i_, m);
      if (s2 < s || (s2 == s && i2 < i_)) { s = s2; i_ = i2; }
    }
    if (l15 == 0) {
      int row32 = ((j >> 2) << 4) + (quad << 2) + (j & 3);   // rt*16 + quad*4 + rr
      unsigned u = __float_as_uint(s);
      u = (u & 0x80000000u) ? ~u : (u | 0x80000000u);        // order-preserving map
      red[wave * 32 + row32] = ((unsigned long long)u << 32) | (unsigned)i_;
    }
  }
  __syncthreads();
  // waves (wh) and (wh+2) cover the same 32 pixel rows with disjoint codes
  if (wave == 0) {
    int wh2 = lane >> 5, r31 = lane & 31;
    unsigned long long a = red[wh2 * 32 + r31];
    unsigned long long b = red[(wh2 + 2) * 32 + r31];
    if (b < a) a = b;
    atomicMin(&best[p0 + lane], a);
  }
}

// ---------------- K3: gather quantized, write codes, accumulate loss ----------------
__global__ void k_gather(const float* __restrict__ z, const float* __restrict__ cb,
                         const unsigned long long* __restrict__ best,
                         float* __restrict__ out_codes, float* __restrict__ out_q,
                         float* __restrict__ lossac) {
  int b  = blockIdx.x >> 4;
  int cg = blockIdx.x & 15;
  int t  = threadIdx.x;
  int idx[4];
#pragma unroll
  for (int pi = 0; pi < 4; ++pi) {
    int p = t + pi * 256;
    unsigned long long pk = best[b * 1024 + p];
    idx[pi] = (int)(unsigned)(pk & 0xffffffffu);
    if (cg == 0) out_codes[b * 1024 + p] = (float)idx[pi];
  }
  float lsum = 0.0f;
#pragma unroll
  for (int ci = 0; ci < 16; ++ci) {
    int c = cg * 16 + ci;
#pragma unroll
    for (int pi = 0; pi < 4; ++pi) {
      int p = t + pi * 256;
      float q  = cb[(size_t)idx[pi] * CDIM + c];
      size_t o = ((size_t)(b * CDIM + c)) * 1024 + p;
      float zv = z[o];
      float d  = q - zv;
      out_q[o] = zv + d;                 // straight-through: same op order as reference
      lsum = fmaf(d, d, lsum);
    }
  }
#pragma unroll
  for (int m = 32; m >= 1; m >>= 1) lsum += __shfl_xor(lsum, m);
  __shared__ float wsum[4];
  if ((t & 63) == 0) wsum[t >> 6] = lsum;
  __syncthreads();
  if (t == 0) atomicAdd(lossac, wsum[0] + wsum[1] + wsum[2] + wsum[3]);
}

// ---------------- K4: finalize loss scalar ----------------
__global__ void k_final(const float* __restrict__ lossac, float* __restrict__ out_loss) {
  if (threadIdx.x == 0) out_loss[0] = lossac[0] * (1.25f / 4194304.0f);
}

extern "C" void kernel_launch(void* const* d_in, const int* in_sizes, int n_in,
                              void* d_out, int out_size, void* d_ws, size_t ws_size,
                              hipStream_t stream) {
  (void)in_sizes; (void)n_in; (void)out_size; (void)ws_size;
  const float* z  = (const float*)d_in[0];
  const float* cb = (const float*)d_in[1];
  float* outf = (float*)d_out;

  char* ws = (char*)d_ws;
  f16*   bfh  = (f16*)ws;                                   // 4 MB packed B-frag hi
  f16*   bfl  = (f16*)(ws + (4 << 20));                     // 4 MB packed B-frag lo
  float* esq  = (float*)(ws + (8 << 20));                   // 32 KB
  unsigned long long* best = (unsigned long long*)(ws + (8 << 20) + 32768);  // 128 KB
  float* lossac = (float*)(ws + (8 << 20) + 32768 + 131072);                 // 4 B (pad 256)
  float* zsq    = (float*)(ws + (8 << 20) + 32768 + 131072 + 256);           // 64 KB
  int*   cnt    = (int*)  (ws + (8 << 20) + 32768 + 131072 + 256 + 65536);   // 32 B

  // scratch inside d_out's quantized region (overwritten by k_gather afterwards)
  f16* zhi = (f16*)(outf + 16384);                          // 8 MB
  f16* zlo = zhi + (size_t)NPIX * CDIM;                     // 8 MB

  k_prep   <<<609,  256, 0,     stream>>>(z, cb, zhi, zlo, zsq, bfh, bfl, esq,
                                          best, lossac, cnt);
  k_score  <<<2048, 256, 65536, stream>>>(bfh, bfl, zhi, zlo, esq, zsq, cnt, best);
  k_gather <<<256,  256, 0,     stream>>>(z, cb, best, outf, outf + 16384, lossac);
  k_final  <<<1,    64,  0,     stream>>>(lossac, outf + 16384 + (size_t)NPIX * CDIM);
}